// Round 1
// baseline (83.990 us; speedup 1.0000x reference)
//
#include <hip/hip_runtime.h>
#include <math.h>

// Problem constants (fixed by reference)
constexpr int N_ = 4, P_ = 64, Z_ = 32, Y_ = 128, X_ = 128;
constexpr float EPSF = 1e-8f;
constexpr float INV2S2 = 0.125f;   // 1/(2*sigma^2), sigma = 2

// Workspace layout (floats)
constexpr int KZ_OFF = 0;                          // [N][P][Z]  8192
constexpr int KY_OFF = KZ_OFF + N_ * P_ * Z_;      // [N][P][Y]  32768
constexpr int KX_OFF = KY_OFF + N_ * P_ * Y_;      // [N][P][X]  32768
constexpr int M_OFF  = KX_OFF + N_ * P_ * X_;      // [N][P]     256
constexpr int TBL_ELEMS = N_ * P_ * (Z_ + Y_ + X_); // 73728

// ---------------------------------------------------------------------------
// Kernel 1: separable Gaussian tables + zero the m accumulator.
// K = exp(-dz^2/8)*exp(-dy^2/8)*exp(-dx^2/8). Safe vs the reference's single
// exp: EPS=1e-8 denominator floor means only K >= ~1e-10 matters (d <= ~14),
// where every factor is a normal fp32 (>= e^-25) -> product == single exp to ulp.
// ---------------------------------------------------------------------------
__global__ __launch_bounds__(256) void k_tables(const float* __restrict__ pts,
                                                float* __restrict__ ws) {
    int idx = blockIdx.x * 256 + threadIdx.x;
    if (idx < N_ * P_) ws[M_OFF + idx] = 0.0f;   // ws is poisoned each call
    if (idx < N_ * P_ * Z_) {
        int n = idx / (P_ * Z_); int r = idx % (P_ * Z_);
        int p = r / Z_; int c = r % Z_;
        float d = (float)c - pts[(n * P_ + p) * 3 + 0];
        ws[KZ_OFF + idx] = expf(-d * d * INV2S2);
    } else if (idx < N_ * P_ * Z_ + N_ * P_ * Y_) {
        int j = idx - N_ * P_ * Z_;
        int n = j / (P_ * Y_); int r = j % (P_ * Y_);
        int p = r / Y_; int c = r % Y_;
        float d = (float)c - pts[(n * P_ + p) * 3 + 1];
        ws[KY_OFF + j] = expf(-d * d * INV2S2);
    } else if (idx < TBL_ELEMS) {
        int j = idx - (N_ * P_ * Z_ + N_ * P_ * Y_);
        int n = j / (P_ * X_); int r = j % (P_ * X_);
        int p = r / X_; int c = r % X_;
        float d = (float)c - pts[(n * P_ + p) * 3 + 2];
        ws[KX_OFF + j] = expf(-d * d * INV2S2);
    }
}

// ---------------------------------------------------------------------------
// Kernel 2: per-voxel denom + m accumulation.
// Grid: 256 blocks = (n, z, y-half). Block: 256 threads = 4 waves.
// Each wave owns one y-row per pass (kzy[row][p] is wave-uniform -> LDS
// broadcast float4 reads). Each thread owns x = lane and x = lane+64, with
// Kx[p] for both columns held in registers so the p-loop is pure v_fma.
// ---------------------------------------------------------------------------
__global__ __launch_bounds__(256) void k_main(const float* __restrict__ logits,
                                              float* __restrict__ ws) {
    const float* kz = ws + KZ_OFF;
    const float* ky = ws + KY_OFF;
    const float* kx = ws + KX_OFF;
    float* m = ws + M_OFF;

    const int b = blockIdx.x;       // 256 blocks
    const int n = b >> 6;           // 64 blocks per n (32 z * 2 y-halves)
    const int z = (b >> 1) & 31;
    const int y0 = (b & 1) * 64;

    const int tid = threadIdx.x;
    const int lane = tid & 63;
    const int wid = tid >> 6;

    __shared__ float kzy[64 * 64];   // [row][p], 16 KB
    __shared__ float wsum[4][64];

    for (int i = tid; i < 64 * 64; i += 256) {
        int row = i >> 6, p = i & 63;
        kzy[i] = kz[(n * P_ + p) * Z_ + z] * ky[(n * P_ + p) * Y_ + (y0 + row)];
    }
    __syncthreads();

    float kxA[64], kxB[64], macc[64];
    #pragma unroll
    for (int p = 0; p < 64; ++p) {
        kxA[p] = kx[(n * P_ + p) * X_ + lane];        // coalesced per p
        kxB[p] = kx[(n * P_ + p) * X_ + lane + 64];
        macc[p] = 0.0f;
    }

    const float* lbase = logits + (size_t)((n * Z_ + z) * Y_ + y0) * X_;

    #pragma unroll 1
    for (int pass = 0; pass < 16; ++pass) {
        const int row = pass * 4 + wid;               // wave-uniform row
        const float lgA = lbase[row * X_ + lane];
        const float lgB = lbase[row * X_ + lane + 64];
        const float sA = 1.0f / (1.0f + expf(-lgA));
        const float sB = 1.0f / (1.0f + expf(-lgB));
        const float4* kr = (const float4*)(&kzy[row * 64]);

        float dA = 0.0f, dB = 0.0f;
        #pragma unroll
        for (int q = 0; q < 16; ++q) {
            const float4 k4 = kr[q];                  // broadcast b128 read
            dA = fmaf(k4.x, kxA[4 * q + 0], dA); dB = fmaf(k4.x, kxB[4 * q + 0], dB);
            dA = fmaf(k4.y, kxA[4 * q + 1], dA); dB = fmaf(k4.y, kxB[4 * q + 1], dB);
            dA = fmaf(k4.z, kxA[4 * q + 2], dA); dB = fmaf(k4.z, kxB[4 * q + 2], dB);
            dA = fmaf(k4.w, kxA[4 * q + 3], dA); dB = fmaf(k4.w, kxB[4 * q + 3], dB);
        }
        const float wA = sA / fmaxf(dA, EPSF);
        const float wB = sB / fmaxf(dB, EPSF);

        #pragma unroll
        for (int q = 0; q < 16; ++q) {
            const float4 k4 = kr[q];
            macc[4*q+0] = fmaf(k4.x, fmaf(kxB[4*q+0], wB, kxA[4*q+0] * wA), macc[4*q+0]);
            macc[4*q+1] = fmaf(k4.y, fmaf(kxB[4*q+1], wB, kxA[4*q+1] * wA), macc[4*q+1]);
            macc[4*q+2] = fmaf(k4.z, fmaf(kxB[4*q+2], wB, kxA[4*q+2] * wA), macc[4*q+2]);
            macc[4*q+3] = fmaf(k4.w, fmaf(kxB[4*q+3], wB, kxA[4*q+3] * wA), macc[4*q+3]);
        }
    }

    // Reduce macc[p] across the 64 lanes of each wave, then across waves.
    #pragma unroll
    for (int p = 0; p < 64; ++p) {
        float v = macc[p];
        #pragma unroll
        for (int off = 32; off > 0; off >>= 1) v += __shfl_xor(v, off, 64);
        macc[p] = v;
    }
    if (lane == 0) {
        #pragma unroll
        for (int p = 0; p < 64; ++p) wsum[wid][p] = macc[p];
    }
    __syncthreads();
    if (tid < 64) {
        float s = wsum[0][tid] + wsum[1][tid] + wsum[2][tid] + wsum[3][tid];
        atomicAdd(&m[n * P_ + tid], s);   // 64 atomics/block, 256 blocks
    }
}

// ---------------------------------------------------------------------------
// Kernel 3: loss = mean_{n,p} -log(max(m, EPS))   (N*P = 256 == block size)
// ---------------------------------------------------------------------------
__global__ __launch_bounds__(256) void k_loss(const float* __restrict__ m,
                                              float* __restrict__ out) {
    int t = threadIdx.x;
    float l = -logf(fmaxf(m[t], EPSF));
    #pragma unroll
    for (int off = 32; off > 0; off >>= 1) l += __shfl_xor(l, off, 64);
    __shared__ float red[4];
    if ((t & 63) == 0) red[t >> 6] = l;
    __syncthreads();
    if (t == 0) out[0] = (red[0] + red[1] + red[2] + red[3]) * (1.0f / 256.0f);
}

extern "C" void kernel_launch(void* const* d_in, const int* in_sizes, int n_in,
                              void* d_out, int out_size, void* d_ws, size_t ws_size,
                              hipStream_t stream) {
    const float* logits = (const float*)d_in[0];  // [4,1,32,128,128] fp32
    const float* pts    = (const float*)d_in[1];  // [4,64,3] fp32
    float* ws  = (float*)d_ws;                    // needs 73984 floats (~289 KB)
    float* out = (float*)d_out;                   // scalar fp32

    k_tables<<<dim3((TBL_ELEMS + 255) / 256), dim3(256), 0, stream>>>(pts, ws);
    k_main<<<dim3(256), dim3(256), 0, stream>>>(logits, ws);
    k_loss<<<dim3(1), dim3(256), 0, stream>>>(ws + M_OFF, out);
}

// Round 2
// 83.821 us; speedup vs baseline: 1.0020x; 1.0020x over previous
//
#include <hip/hip_runtime.h>
#include <math.h>

// Problem constants (fixed by reference)
constexpr int N_ = 4, P_ = 64, Z_ = 32, Y_ = 128, X_ = 128;
constexpr float EPSF = 1e-8f;
constexpr float INV2S2 = 0.125f;   // 1/(2*sigma^2), sigma = 2

// Workspace layout (floats)
constexpr int KZ_OFF = 0;                          // [N][P][Z]  8192
constexpr int KY_OFF = KZ_OFF + N_ * P_ * Z_;      // [N][P][Y]  32768
constexpr int KX_OFF = KY_OFF + N_ * P_ * Y_;      // [N][P][X]  32768
constexpr int M_OFF  = KX_OFF + N_ * P_ * X_;      // [N][P]     256
constexpr int TBL_ELEMS = N_ * P_ * (Z_ + Y_ + X_); // 73728

// ---------------------------------------------------------------------------
// Kernel 1: separable Gaussian tables + zero the m accumulator.
// K = exp(-dz^2/8)*exp(-dy^2/8)*exp(-dx^2/8). Safe vs the reference's single
// exp: EPS=1e-8 denominator floor means only K >= ~1e-10 matters (d <= ~14),
// where every factor is a normal fp32 (>= e^-25) -> product == single exp to ulp.
// ---------------------------------------------------------------------------
__global__ __launch_bounds__(256) void k_tables(const float* __restrict__ pts,
                                                float* __restrict__ ws) {
    int idx = blockIdx.x * 256 + threadIdx.x;
    if (idx < N_ * P_) ws[M_OFF + idx] = 0.0f;   // ws is poisoned each call
    if (idx < N_ * P_ * Z_) {
        int n = idx / (P_ * Z_); int r = idx % (P_ * Z_);
        int p = r / Z_; int c = r % Z_;
        float d = (float)c - pts[(n * P_ + p) * 3 + 0];
        ws[KZ_OFF + idx] = expf(-d * d * INV2S2);
    } else if (idx < N_ * P_ * Z_ + N_ * P_ * Y_) {
        int j = idx - N_ * P_ * Z_;
        int n = j / (P_ * Y_); int r = j % (P_ * Y_);
        int p = r / Y_; int c = r % Y_;
        float d = (float)c - pts[(n * P_ + p) * 3 + 1];
        ws[KY_OFF + j] = expf(-d * d * INV2S2);
    } else if (idx < TBL_ELEMS) {
        int j = idx - (N_ * P_ * Z_ + N_ * P_ * Y_);
        int n = j / (P_ * X_); int r = j % (P_ * X_);
        int p = r / X_; int c = r % X_;
        float d = (float)c - pts[(n * P_ + p) * 3 + 2];
        ws[KX_OFF + j] = expf(-d * d * INV2S2);
    }
}

// ---------------------------------------------------------------------------
// Kernel 2: per-voxel denom + m accumulation.
// Grid: 256 blocks = (n, z, y-half). Block: 256 threads = 4 waves.
// Each wave owns one y-row per pass (kzy[row][p] is wave-uniform -> LDS
// broadcast float4 reads). Each thread owns x = lane and x = lane+64, with
// Kx[p] for both columns held in registers so the p-loop is pure v_fma.
//
// __launch_bounds__(256, 1): 1 wave/EU -> VGPR cap 512. The per-thread state
// (kxA[64]+kxB[64]+macc[64] ~= 220 VGPRs) MUST stay register-resident; the
// default occupancy target caps at ~128 VGPRs and spills ~100 floats/thread
// to scratch, which dominated R0's runtime. Grid is 256 blocks = 1 block/CU,
// so capping at 1 block/CU costs nothing.
// ---------------------------------------------------------------------------
__global__ __launch_bounds__(256, 1) void k_main(const float* __restrict__ logits,
                                                 float* __restrict__ ws) {
    const float* kz = ws + KZ_OFF;
    const float* ky = ws + KY_OFF;
    const float* kx = ws + KX_OFF;
    float* m = ws + M_OFF;

    const int b = blockIdx.x;       // 256 blocks
    const int n = b >> 6;           // 64 blocks per n (32 z * 2 y-halves)
    const int z = (b >> 1) & 31;
    const int y0 = (b & 1) * 64;

    const int tid = threadIdx.x;
    const int lane = tid & 63;
    const int wid = tid >> 6;

    __shared__ float kzy[64 * 64];   // [row][p], 16 KB
    __shared__ float wsum[4][64];

    for (int i = tid; i < 64 * 64; i += 256) {
        int row = i >> 6, p = i & 63;
        kzy[i] = kz[(n * P_ + p) * Z_ + z] * ky[(n * P_ + p) * Y_ + (y0 + row)];
    }
    __syncthreads();

    float kxA[64], kxB[64], macc[64];
    #pragma unroll
    for (int p = 0; p < 64; ++p) {
        kxA[p] = kx[(n * P_ + p) * X_ + lane];        // coalesced per p
        kxB[p] = kx[(n * P_ + p) * X_ + lane + 64];
        macc[p] = 0.0f;
    }

    const float* lbase = logits + (size_t)((n * Z_ + z) * Y_ + y0) * X_;

    #pragma unroll 1
    for (int pass = 0; pass < 16; ++pass) {
        const int row = pass * 4 + wid;               // wave-uniform row
        const float lgA = lbase[row * X_ + lane];
        const float lgB = lbase[row * X_ + lane + 64];
        const float4* kr = (const float4*)(&kzy[row * 64]);

        float dA = 0.0f, dB = 0.0f;
        #pragma unroll
        for (int q = 0; q < 16; ++q) {
            const float4 k4 = kr[q];                  // broadcast b128 read
            dA = fmaf(k4.x, kxA[4 * q + 0], dA); dB = fmaf(k4.x, kxB[4 * q + 0], dB);
            dA = fmaf(k4.y, kxA[4 * q + 1], dA); dB = fmaf(k4.y, kxB[4 * q + 1], dB);
            dA = fmaf(k4.z, kxA[4 * q + 2], dA); dB = fmaf(k4.z, kxB[4 * q + 2], dB);
            dA = fmaf(k4.w, kxA[4 * q + 3], dA); dB = fmaf(k4.w, kxB[4 * q + 3], dB);
        }
        // w = sigmoid(lg) / max(d, EPS) = 1 / ((1+e^-lg) * max(d, EPS)):
        // one fp32 divide instead of two.
        const float wA = 1.0f / ((1.0f + expf(-lgA)) * fmaxf(dA, EPSF));
        const float wB = 1.0f / ((1.0f + expf(-lgB)) * fmaxf(dB, EPSF));

        #pragma unroll
        for (int q = 0; q < 16; ++q) {
            const float4 k4 = kr[q];
            macc[4*q+0] = fmaf(k4.x, fmaf(kxB[4*q+0], wB, kxA[4*q+0] * wA), macc[4*q+0]);
            macc[4*q+1] = fmaf(k4.y, fmaf(kxB[4*q+1], wB, kxA[4*q+1] * wA), macc[4*q+1]);
            macc[4*q+2] = fmaf(k4.z, fmaf(kxB[4*q+2], wB, kxA[4*q+2] * wA), macc[4*q+2]);
            macc[4*q+3] = fmaf(k4.w, fmaf(kxB[4*q+3], wB, kxA[4*q+3] * wA), macc[4*q+3]);
        }
    }

    // Reduce macc[p] across the 64 lanes of each wave, then across waves.
    #pragma unroll
    for (int p = 0; p < 64; ++p) {
        float v = macc[p];
        #pragma unroll
        for (int off = 32; off > 0; off >>= 1) v += __shfl_xor(v, off, 64);
        macc[p] = v;
    }
    if (lane == 0) {
        #pragma unroll
        for (int p = 0; p < 64; ++p) wsum[wid][p] = macc[p];
    }
    __syncthreads();
    if (tid < 64) {
        float s = wsum[0][tid] + wsum[1][tid] + wsum[2][tid] + wsum[3][tid];
        atomicAdd(&m[n * P_ + tid], s);   // 64 atomics/block, 256 blocks
    }
}

// ---------------------------------------------------------------------------
// Kernel 3: loss = mean_{n,p} -log(max(m, EPS))   (N*P = 256 == block size)
// ---------------------------------------------------------------------------
__global__ __launch_bounds__(256) void k_loss(const float* __restrict__ m,
                                              float* __restrict__ out) {
    int t = threadIdx.x;
    float l = -logf(fmaxf(m[t], EPSF));
    #pragma unroll
    for (int off = 32; off > 0; off >>= 1) l += __shfl_xor(l, off, 64);
    __shared__ float red[4];
    if ((t & 63) == 0) red[t >> 6] = l;
    __syncthreads();
    if (t == 0) out[0] = (red[0] + red[1] + red[2] + red[3]) * (1.0f / 256.0f);
}

extern "C" void kernel_launch(void* const* d_in, const int* in_sizes, int n_in,
                              void* d_out, int out_size, void* d_ws, size_t ws_size,
                              hipStream_t stream) {
    const float* logits = (const float*)d_in[0];  // [4,1,32,128,128] fp32
    const float* pts    = (const float*)d_in[1];  // [4,64,3] fp32
    float* ws  = (float*)d_ws;                    // needs 73984 floats (~289 KB)
    float* out = (float*)d_out;                   // scalar fp32

    k_tables<<<dim3((TBL_ELEMS + 255) / 256), dim3(256), 0, stream>>>(pts, ws);
    k_main<<<dim3(256), dim3(256), 0, stream>>>(logits, ws);
    k_loss<<<dim3(1), dim3(256), 0, stream>>>(ws + M_OFF, out);
}